// Round 1
// baseline (585.369 us; speedup 1.0000x reference)
//
#include <hip/hip_runtime.h>
#include <hip/hip_bf16.h>

#define B_   4
#define TQ_  2048
#define TKV_ 2048
#define DM_  1024
#define H_   16
#define DH_  64

using f32x4 = __attribute__((ext_vector_type(4))) float;
using s16x8 = __attribute__((ext_vector_type(8))) short;

static __device__ __forceinline__ unsigned short f2bf(float f) {
  union { float f; unsigned int u; } v; v.f = f;
  unsigned int r = v.u + 0x7FFFu + ((v.u >> 16) & 1u);
  return (unsigned short)(r >> 16);
}

// ---------------- transpose + cast: W[K][N] f32 -> WT[N][K] bf16 ----------------
__global__ __launch_bounds__(256) void k_transpose_cast(
    const float* __restrict__ W, unsigned short* __restrict__ WT, int K, int N) {
  __shared__ float t[64][65];
  int n0 = blockIdx.x * 64, k0 = blockIdx.y * 64;
  int tx = threadIdx.x & 63, ty = threadIdx.x >> 6;
#pragma unroll
  for (int i = 0; i < 64; i += 4)
    t[ty + i][tx] = W[(size_t)(k0 + ty + i) * N + n0 + tx];
  __syncthreads();
#pragma unroll
  for (int i = 0; i < 64; i += 4)
    WT[(size_t)(n0 + ty + i) * K + k0 + tx] = f2bf(t[tx][ty + i]);
}

// ---------------- GEMM: C[m][n] = A[m][:] . BT[n][:] + bias[n] ----------------
// MODE 0: write Q [B,H,T,64] bf16   MODE 1: write K,V [B,H,T,64] bf16
// MODE 2: write fp32 out [m][n]
template <int MODE, bool A_BF16>
__global__ __launch_bounds__(256) void k_gemm(
    const void* __restrict__ Ap, const unsigned short* __restrict__ BT,
    const float* __restrict__ bias, unsigned short* __restrict__ out_a,
    unsigned short* __restrict__ out_b, float* __restrict__ out_f, int Kd) {
  __shared__ unsigned short As[128][40];
  __shared__ unsigned short Bs[128][40];
  int tid = threadIdx.x;
  int lane = tid & 63;
  int wv = tid >> 6;
  int wm = wv >> 1, wn = wv & 1;
  int m0 = blockIdx.y * 128, n0 = blockIdx.x * 128;

  f32x4 acc[4][4];
#pragma unroll
  for (int i = 0; i < 4; ++i)
#pragma unroll
    for (int j = 0; j < 4; ++j) acc[i][j] = (f32x4){0.f, 0.f, 0.f, 0.f};

  for (int k0 = 0; k0 < Kd; k0 += 32) {
    // ---- stage A tile (128 x 32) ----
    if (A_BF16) {
      const unsigned short* A = (const unsigned short*)Ap;
#pragma unroll
      for (int i = 0; i < 2; ++i) {
        int row = i * 64 + (tid >> 2);
        int c = (tid & 3) * 8;
        s16x8 v = *(const s16x8*)(A + (size_t)(m0 + row) * Kd + k0 + c);
        *(s16x8*)(&As[row][c]) = v;
      }
    } else {
      const float* A = (const float*)Ap;
#pragma unroll
      for (int i = 0; i < 4; ++i) {
        int row = i * 32 + (tid >> 3);
        int c = (tid & 7) * 4;
        f32x4 g = *(const f32x4*)(A + (size_t)(m0 + row) * Kd + k0 + c);
        union { unsigned short h[4]; unsigned long long u; } p;
#pragma unroll
        for (int j = 0; j < 4; ++j) p.h[j] = f2bf(g[j]);
        *(unsigned long long*)(&As[row][c]) = p.u;
      }
    }
    // ---- stage B tile (128 n-rows x 32 k), BT is [N][K] bf16 ----
#pragma unroll
    for (int i = 0; i < 2; ++i) {
      int row = i * 64 + (tid >> 2);
      int c = (tid & 3) * 8;
      s16x8 v = *(const s16x8*)(BT + (size_t)(n0 + row) * Kd + k0 + c);
      *(s16x8*)(&Bs[row][c]) = v;
    }
    __syncthreads();
    s16x8 af[4], bf[4];
#pragma unroll
    for (int i = 0; i < 4; ++i) {
      af[i] = *(const s16x8*)(&As[wm * 64 + i * 16 + (lane & 15)][(lane >> 4) * 8]);
      bf[i] = *(const s16x8*)(&Bs[wn * 64 + i * 16 + (lane & 15)][(lane >> 4) * 8]);
    }
#pragma unroll
    for (int mi = 0; mi < 4; ++mi)
#pragma unroll
      for (int ni = 0; ni < 4; ++ni)
        acc[mi][ni] = __builtin_amdgcn_mfma_f32_16x16x32_bf16(af[mi], bf[ni], acc[mi][ni], 0, 0, 0);
    __syncthreads();
  }

  // ---- epilogue: C row = (lane>>4)*4+reg, col = lane&15 ----
#pragma unroll
  for (int mi = 0; mi < 4; ++mi) {
#pragma unroll
    for (int ni = 0; ni < 4; ++ni) {
      int col = n0 + wn * 64 + ni * 16 + (lane & 15);
      int rbase = m0 + wm * 64 + mi * 16 + (lane >> 4) * 4;
      float bv = bias[col];
#pragma unroll
      for (int r = 0; r < 4; ++r) {
        float v = acc[mi][ni][r] + bv;
        int m = rbase + r;
        if (MODE == 0) {
          int b = m >> 11, t = m & 2047;
          int h = col >> 6, d = col & 63;
          out_a[(((size_t)b * H_ + h) * TQ_ + t) * DH_ + d] = f2bf(v);
        } else if (MODE == 1) {
          int b = m >> 11, t = m & 2047;
          if (col < H_ * DH_) {
            int h = col >> 6, d = col & 63;
            out_a[(((size_t)b * H_ + h) * TKV_ + t) * DH_ + d] = f2bf(v);
          } else {
            int c2 = col - H_ * DH_;
            int h = c2 >> 6, d = c2 & 63;
            out_b[(((size_t)b * H_ + h) * TKV_ + t) * DH_ + d] = f2bf(v);
          }
        } else {
          out_f[(size_t)m * DM_ + col] = v;
        }
      }
    }
  }
}

// ---------------- flash attention ----------------
// grid: (TQ/64, B*H), 256 threads (4 waves x 16 q-rows), KV chunks of 32
__global__ __launch_bounds__(256) void k_attn(
    const unsigned short* __restrict__ Qb, const unsigned short* __restrict__ Kb,
    const unsigned short* __restrict__ Vb, const unsigned char* __restrict__ mask,
    const int* __restrict__ cflag, unsigned short* __restrict__ Ob) {
  __shared__ unsigned short Kt[32][72];   // [kv][d]  (+8 pad)
  __shared__ unsigned short Vt[64][40];   // [d][kv]  (+8 pad), transposed
  __shared__ unsigned short Pl[4][16][40];// per-wave P tile [qrow][kv] (+8 pad)

  int bh = blockIdx.y;
  int b = bh >> 4;
  int q0 = blockIdx.x * 64;
  int tid = threadIdx.x, lane = tid & 63, w = tid >> 6;
  const unsigned short* Qp = Qb + (size_t)bh * TQ_ * DH_;
  const unsigned short* Kp = Kb + (size_t)bh * TKV_ * DH_;
  const unsigned short* Vp = Vb + (size_t)bh * TKV_ * DH_;
  const unsigned char* mp = mask + (size_t)b * TKV_;

  // Q fragments held in registers for the whole block
  int qrow_frag = q0 + w * 16 + (lane & 15);
  s16x8 aq[2];
  aq[0] = *(const s16x8*)(Qp + (size_t)qrow_frag * DH_ + (lane >> 4) * 8);
  aq[1] = *(const s16x8*)(Qp + (size_t)qrow_frag * DH_ + 32 + (lane >> 4) * 8);

  f32x4 accO[4];
#pragma unroll
  for (int i = 0; i < 4; ++i) accO[i] = (f32x4){0.f, 0.f, 0.f, 0.f};
  float mrow[4] = {-INFINITY, -INFINITY, -INFINITY, -INFINITY};
  float lrow[4] = {0.f, 0.f, 0.f, 0.f};

  int causal = *cflag;
  int kv_end = causal ? (q0 + 64) : TKV_;
  const float sc = 0.125f * 1.44269504088896f;  // 1/sqrt(64) * log2(e)

  for (int kv0 = 0; kv0 < kv_end; kv0 += 32) {
    __syncthreads();
    {  // cooperative staging: K tile + transposed V tile
      int row = tid >> 3, c = (tid & 7) * 8;
      s16x8 kvv = *(const s16x8*)(Kp + (size_t)(kv0 + row) * DH_ + c);
      *(s16x8*)(&Kt[row][c]) = kvv;
      s16x8 vvv = *(const s16x8*)(Vp + (size_t)(kv0 + row) * DH_ + c);
#pragma unroll
      for (int j = 0; j < 8; ++j) Vt[c + j][row] = (unsigned short)vvv[j];
    }
    __syncthreads();
    if (causal && kv0 > q0 + w * 16 + 15) continue;  // wave fully above diagonal

    // S = Q K^T  (16 q-rows x 32 kv-cols per wave)
    f32x4 s0 = (f32x4){0.f, 0.f, 0.f, 0.f};
    f32x4 s1 = (f32x4){0.f, 0.f, 0.f, 0.f};
#pragma unroll
    for (int kk = 0; kk < 2; ++kk) {
      s16x8 bk0 = *(const s16x8*)(&Kt[lane & 15][kk * 32 + (lane >> 4) * 8]);
      s16x8 bk1 = *(const s16x8*)(&Kt[16 + (lane & 15)][kk * 32 + (lane >> 4) * 8]);
      s0 = __builtin_amdgcn_mfma_f32_16x16x32_bf16(aq[kk], bk0, s0, 0, 0, 0);
      s1 = __builtin_amdgcn_mfma_f32_16x16x32_bf16(aq[kk], bk1, s1, 0, 0, 0);
    }

    // scale + masks
    int col0 = kv0 + (lane & 15);
    int col1 = col0 + 16;
    int rq = q0 + w * 16 + (lane >> 4) * 4;
    unsigned char mb0 = mp[col0], mb1 = mp[col1];
#pragma unroll
    for (int r = 0; r < 4; ++r) {
      float v0 = s0[r] * sc, v1 = s1[r] * sc;
      bool d0 = mb0 || (causal && col0 > rq + r);
      bool d1 = mb1 || (causal && col1 > rq + r);
      s0[r] = d0 ? -1e30f : v0;
      s1[r] = d1 ? -1e30f : v1;
    }

    // online softmax (base-2), rows live in 16-lane groups
#pragma unroll
    for (int r = 0; r < 4; ++r) {
      float mx = fmaxf(s0[r], s1[r]);
      mx = fmaxf(mx, __shfl_xor(mx, 1));
      mx = fmaxf(mx, __shfl_xor(mx, 2));
      mx = fmaxf(mx, __shfl_xor(mx, 4));
      mx = fmaxf(mx, __shfl_xor(mx, 8));
      float mo = mrow[r];
      float mn = fmaxf(mo, mx);
      float scale = exp2f(mo - mn);
      float p0 = exp2f(s0[r] - mn);
      float p1 = exp2f(s1[r] - mn);
      s0[r] = p0; s1[r] = p1;
      float ps = p0 + p1;
      ps += __shfl_xor(ps, 1);
      ps += __shfl_xor(ps, 2);
      ps += __shfl_xor(ps, 4);
      ps += __shfl_xor(ps, 8);
      lrow[r] = lrow[r] * scale + ps;
      mrow[r] = mn;
      accO[0][r] *= scale; accO[1][r] *= scale;
      accO[2][r] *= scale; accO[3][r] *= scale;
    }

    // P -> per-wave LDS (C-layout -> A-layout redistribution)
    int prow = (lane >> 4) * 4;
#pragma unroll
    for (int r = 0; r < 4; ++r) {
      Pl[w][prow + r][lane & 15] = f2bf(s0[r]);
      Pl[w][prow + r][16 + (lane & 15)] = f2bf(s1[r]);
    }
    asm volatile("s_waitcnt lgkmcnt(0)" ::: "memory");
    s16x8 ap = *(const s16x8*)(&Pl[w][lane & 15][(lane >> 4) * 8]);

    // O += P V
#pragma unroll
    for (int ni = 0; ni < 4; ++ni) {
      s16x8 bv = *(const s16x8*)(&Vt[ni * 16 + (lane & 15)][(lane >> 4) * 8]);
      accO[ni] = __builtin_amdgcn_mfma_f32_16x16x32_bf16(ap, bv, accO[ni], 0, 0, 0);
    }
  }

  // epilogue: divide by l, write Ob[B][TQ][H*64] bf16
  int h = bh & 15;
#pragma unroll
  for (int r = 0; r < 4; ++r) {
    int row = q0 + w * 16 + (lane >> 4) * 4 + r;
    float inv = 1.0f / lrow[r];
#pragma unroll
    for (int ni = 0; ni < 4; ++ni) {
      float v = accO[ni][r] * inv;
      int d = ni * 16 + (lane & 15);
      Ob[((size_t)b * TQ_ + row) * DM_ + h * DH_ + d] = f2bf(v);
    }
  }
}

extern "C" void kernel_launch(void* const* d_in, const int* in_sizes, int n_in,
                              void* d_out, int out_size, void* d_ws, size_t ws_size,
                              hipStream_t stream) {
  const float* xq  = (const float*)d_in[0];
  const float* xkv = (const float*)d_in[1];
  const unsigned char* mask = (const unsigned char*)d_in[2];
  const float* Wq  = (const float*)d_in[3];
  const float* bq  = (const float*)d_in[4];
  const float* Wkv = (const float*)d_in[5];
  const float* bkv = (const float*)d_in[6];
  const float* Wo  = (const float*)d_in[7];
  const float* bo  = (const float*)d_in[8];
  const int* cflag = (const int*)d_in[9];
  float* out = (float*)d_out;

  char* ws = (char*)d_ws;
  unsigned short* WqT  = (unsigned short*)(ws);                       // [1024][1024] bf16, 2 MiB
  unsigned short* WkvT = (unsigned short*)(ws + ((size_t)2 << 20));   // [2048][1024] bf16, 4 MiB
  unsigned short* WoT  = (unsigned short*)(ws + ((size_t)6 << 20));   // [1024][1024] bf16, 2 MiB
  unsigned short* Qb   = (unsigned short*)(ws + ((size_t)8 << 20));   // [B,H,TQ,64] bf16, 16 MiB
  unsigned short* Kb   = (unsigned short*)(ws + ((size_t)24 << 20));  // 16 MiB
  unsigned short* Vb   = (unsigned short*)(ws + ((size_t)40 << 20));  // 16 MiB
  unsigned short* Ob   = (unsigned short*)(ws + ((size_t)56 << 20));  // [B,TQ,1024] bf16, 16 MiB

  // weights -> bf16 [N][K]
  k_transpose_cast<<<dim3(16, 16), 256, 0, stream>>>(Wq, WqT, 1024, 1024);
  k_transpose_cast<<<dim3(32, 16), 256, 0, stream>>>(Wkv, WkvT, 1024, 2048);
  k_transpose_cast<<<dim3(16, 16), 256, 0, stream>>>(Wo, WoT, 1024, 1024);

  // projections
  k_gemm<0, false><<<dim3(8, 64), 256, 0, stream>>>(xq, WqT, bq, Qb, nullptr, nullptr, 1024);
  k_gemm<1, false><<<dim3(16, 64), 256, 0, stream>>>(xkv, WkvT, bkv, Kb, Vb, nullptr, 1024);

  // attention
  k_attn<<<dim3(TQ_ / 64, B_ * H_), 256, 0, stream>>>(Qb, Kb, Vb, mask, cflag, Ob);

  // output projection (fp32 out + bias)
  k_gemm<2, true><<<dim3(8, 64), 256, 0, stream>>>(Ob, WoT, bo, nullptr, nullptr, out, 1024);
}

// Round 2
// 344.757 us; speedup vs baseline: 1.6979x; 1.6979x over previous
//
#include <hip/hip_runtime.h>
#include <hip/hip_bf16.h>

#define B_   4
#define TQ_  2048
#define TKV_ 2048
#define DM_  1024
#define H_   16
#define DH_  64

using f32x4  = __attribute__((ext_vector_type(4))) float;
using f32x16 = __attribute__((ext_vector_type(16))) float;
using s16x8  = __attribute__((ext_vector_type(8))) short;

static __device__ __forceinline__ unsigned short f2bf(float f) {
  union { float f; unsigned int u; } v; v.f = f;
  unsigned int r = v.u + 0x7FFFu + ((v.u >> 16) & 1u);
  return (unsigned short)(r >> 16);
}
static __device__ __forceinline__ unsigned int pk2(float a, float b) {
  return (unsigned int)f2bf(a) | ((unsigned int)f2bf(b) << 16);
}

// ---------------- transpose + cast: W[K][N] f32 -> WT[N][K] bf16 ----------------
__global__ __launch_bounds__(256) void k_transpose_cast(
    const float* __restrict__ W, unsigned short* __restrict__ WT, int K, int N) {
  __shared__ float t[64][65];
  int n0 = blockIdx.x * 64, k0 = blockIdx.y * 64;
  int tx = threadIdx.x & 63, ty = threadIdx.x >> 6;
#pragma unroll
  for (int i = 0; i < 64; i += 4)
    t[ty + i][tx] = W[(size_t)(k0 + ty + i) * N + n0 + tx];
  __syncthreads();
#pragma unroll
  for (int i = 0; i < 64; i += 4)
    WT[(size_t)(n0 + ty + i) * K + k0 + tx] = f2bf(t[tx][ty + i]);
}

// ---------------- GEMM: C[m][n] = A[m][:] . BT[n][:] + bias[n] ----------------
// MODE 0: write Q [B,H,T,64] bf16
// MODE 1: write K [B,H,T,64] bf16, V TRANSPOSED [B,H,64,TKV] bf16
// MODE 2: write fp32 out [m][n]
template <int MODE, bool A_BF16>
__global__ __launch_bounds__(256) void k_gemm(
    const void* __restrict__ Ap, const unsigned short* __restrict__ BT,
    const float* __restrict__ bias, unsigned short* __restrict__ out_a,
    unsigned short* __restrict__ out_b, float* __restrict__ out_f, int Kd) {
  __shared__ unsigned short As[128][40];
  __shared__ unsigned short Bs[128][40];
  int tid = threadIdx.x;
  int lane = tid & 63;
  int wv = tid >> 6;
  int wm = wv >> 1, wn = wv & 1;
  int m0 = blockIdx.y * 128, n0 = blockIdx.x * 128;

  f32x4 acc[4][4];
#pragma unroll
  for (int i = 0; i < 4; ++i)
#pragma unroll
    for (int j = 0; j < 4; ++j) acc[i][j] = (f32x4){0.f, 0.f, 0.f, 0.f};

  for (int k0 = 0; k0 < Kd; k0 += 32) {
    if (A_BF16) {
      const unsigned short* A = (const unsigned short*)Ap;
#pragma unroll
      for (int i = 0; i < 2; ++i) {
        int row = i * 64 + (tid >> 2);
        int c = (tid & 3) * 8;
        s16x8 v = *(const s16x8*)(A + (size_t)(m0 + row) * Kd + k0 + c);
        *(s16x8*)(&As[row][c]) = v;
      }
    } else {
      const float* A = (const float*)Ap;
#pragma unroll
      for (int i = 0; i < 4; ++i) {
        int row = i * 32 + (tid >> 3);
        int c = (tid & 7) * 4;
        f32x4 g = *(const f32x4*)(A + (size_t)(m0 + row) * Kd + k0 + c);
        union { unsigned short h[4]; unsigned long long u; } p;
#pragma unroll
        for (int j = 0; j < 4; ++j) p.h[j] = f2bf(g[j]);
        *(unsigned long long*)(&As[row][c]) = p.u;
      }
    }
#pragma unroll
    for (int i = 0; i < 2; ++i) {
      int row = i * 64 + (tid >> 2);
      int c = (tid & 3) * 8;
      s16x8 v = *(const s16x8*)(BT + (size_t)(n0 + row) * Kd + k0 + c);
      *(s16x8*)(&Bs[row][c]) = v;
    }
    __syncthreads();
    s16x8 af[4], bf[4];
#pragma unroll
    for (int i = 0; i < 4; ++i) {
      af[i] = *(const s16x8*)(&As[wm * 64 + i * 16 + (lane & 15)][(lane >> 4) * 8]);
      bf[i] = *(const s16x8*)(&Bs[wn * 64 + i * 16 + (lane & 15)][(lane >> 4) * 8]);
    }
#pragma unroll
    for (int mi = 0; mi < 4; ++mi)
#pragma unroll
      for (int ni = 0; ni < 4; ++ni)
        acc[mi][ni] = __builtin_amdgcn_mfma_f32_16x16x32_bf16(af[mi], bf[ni], acc[mi][ni], 0, 0, 0);
    __syncthreads();
  }

#pragma unroll
  for (int mi = 0; mi < 4; ++mi) {
#pragma unroll
    for (int ni = 0; ni < 4; ++ni) {
      int col = n0 + wn * 64 + ni * 16 + (lane & 15);
      int rbase = m0 + wm * 64 + mi * 16 + (lane >> 4) * 4;
      float bv = bias[col];
      if (MODE == 1 && col >= H_ * DH_) {
        // V^T: [B,H,64,TKV]; t = rbase..rbase+3 contiguous -> one 8B store
        int c2 = col - H_ * DH_;
        int h = c2 >> 6, d = c2 & 63;
        int b = rbase >> 11, t = rbase & 2047;
        union { unsigned short h4[4]; unsigned long long u; } p;
#pragma unroll
        for (int r = 0; r < 4; ++r) p.h4[r] = f2bf(acc[mi][ni][r] + bv);
        *(unsigned long long*)(out_b + ((((size_t)b * H_ + h) * DH_ + d) * TKV_ + t)) = p.u;
      } else {
#pragma unroll
        for (int r = 0; r < 4; ++r) {
          float v = acc[mi][ni][r] + bv;
          int m = rbase + r;
          if (MODE == 0) {
            int b = m >> 11, t = m & 2047;
            int h = col >> 6, d = col & 63;
            out_a[(((size_t)b * H_ + h) * TQ_ + t) * DH_ + d] = f2bf(v);
          } else if (MODE == 1) {
            int b = m >> 11, t = m & 2047;
            int h = col >> 6, d = col & 63;
            out_a[(((size_t)b * H_ + h) * TKV_ + t) * DH_ + d] = f2bf(v);
          } else {
            out_f[(size_t)m * DM_ + col] = v;
          }
        }
      }
    }
  }
}

// ---------------- flash attention, swapped-QK^T 32x32 structure ----------------
// grid: (TQ/128, B*H), 256 threads = 4 waves x 32 q-rows, KV tiles of 64.
// S^T = K·Q^T via mfma(A=K-frag, B=Q-frag): lane owns q = lane&31, 32 of the
// 64 kv values in-register (other half in lane^32) -> in-lane softmax.
__global__ __launch_bounds__(256, 3) void k_attn(
    const unsigned short* __restrict__ Qb, const unsigned short* __restrict__ Kb,
    const unsigned short* __restrict__ Vtb, const unsigned char* __restrict__ mask,
    const int* __restrict__ cflag, unsigned short* __restrict__ Ob) {
  __shared__ __align__(16) unsigned short Kt[64 * 64];  // [kv][d], XOR-swizzled
  __shared__ __align__(16) unsigned short Vt[64 * 64];  // [d][kv], XOR-swizzled
  __shared__ float bias_lds[64];
  __shared__ float red[4][32];

  int bh = blockIdx.y;
  int b = bh >> 4, h = bh & 15;
  int qb = blockIdx.x * 128;
  int tid = threadIdx.x, lane = tid & 63, w = tid >> 6;
  int hi = lane >> 5, l31 = lane & 31, l7 = lane & 7;
  const unsigned short* Qp = Qb + (size_t)bh * TQ_ * DH_;
  const char* Kp = (const char*)(Kb + (size_t)bh * TKV_ * DH_);
  const char* Vp = (const char*)(Vtb + (size_t)bh * DH_ * TKV_);
  const unsigned char* mp = mask + (size_t)b * TKV_;
  int causal = cflag[0];
  int qw = qb + w * 32;
  int qrow = qw + l31;

  // Q B-fragments (lane: col q = l31, k = d = kk*16 + hi*8 .. +8)
  s16x8 bQ[4];
#pragma unroll
  for (int kk = 0; kk < 4; ++kk)
    bQ[kk] = *(const s16x8*)(Qp + (size_t)qrow * DH_ + kk * 16 + hi * 8);

  f32x16 accO[2];
#pragma unroll
  for (int i = 0; i < 16; ++i) { accO[0][i] = 0.f; accO[1][i] = 0.f; }
  float m_run = -INFINITY, l_run = 0.f;
  const float sc = 0.125f * 1.44269504088896f;

  char* kbase = (char*)Kt;
  char* vbase = (char*)Vt;
  int kv_end = causal ? (qb + 128) : TKV_;

  for (int kv0 = 0; kv0 < kv_end; kv0 += 64) {
    __syncthreads();
    {  // stage K tile [64][64] and V^T tile [64][64], swizzled writes
      int row = tid >> 2;
      int cb0 = (tid & 3) * 16;
#pragma unroll
      for (int p = 0; p < 2; ++p) {
        int cb = cb0 + p * 64;
        int sw = cb ^ ((row & 7) << 4);
        s16x8 kvv = *(const s16x8*)(Kp + ((size_t)(kv0 + row) * 128 + cb));
        *(s16x8*)(kbase + row * 128 + sw) = kvv;
        s16x8 vvv = *(const s16x8*)(Vp + (((size_t)row * TKV_ + kv0) * 2 + cb));
        *(s16x8*)(vbase + row * 128 + sw) = vvv;
      }
      if (tid < 64) bias_lds[tid] = mp[kv0 + tid] ? -1e30f : 0.0f;
    }
    __syncthreads();
    if (causal && kv0 >= qw + 32) continue;  // wave fully above diagonal

    // S^T = K . Q^T  (64 kv x 32 q per wave, two 32x32 sub-tiles)
    f32x16 sT[2];
#pragma unroll
    for (int i = 0; i < 16; ++i) { sT[0][i] = 0.f; sT[1][i] = 0.f; }
#pragma unroll
    for (int s = 0; s < 2; ++s) {
#pragma unroll
      for (int kk = 0; kk < 4; ++kk) {
        s16x8 aK = *(const s16x8*)(kbase + (s * 32 + l31) * 128 +
                                   ((kk * 32 + hi * 16) ^ (l7 << 4)));
        sT[s] = __builtin_amdgcn_mfma_f32_32x32x16_bf16(aK, bQ[kk], sT[s], 0, 0, 0);
      }
    }

    // scale + masks + in-lane max over 32 regs
    float mx = -INFINITY;
#pragma unroll
    for (int s = 0; s < 2; ++s) {
#pragma unroll
      for (int r = 0; r < 16; ++r) {
        int kvloc = s * 32 + (r & 3) + 8 * (r >> 2) + 4 * hi;
        float sv = sT[s][r] * sc + bias_lds[kvloc];
        if (causal && (kv0 + kvloc) > qrow) sv = -1e30f;
        sT[s][r] = sv;
        mx = fmaxf(mx, sv);
      }
    }
    mx = fmaxf(mx, __shfl_xor(mx, 32));
    float mnew = fmaxf(m_run, mx);
    float sc_o = exp2f(m_run - mnew);
    m_run = mnew;
    float ls = 0.f;
#pragma unroll
    for (int s = 0; s < 2; ++s)
#pragma unroll
      for (int r = 0; r < 16; ++r) {
        float p = exp2f(sT[s][r] - mnew);
        sT[s][r] = p;
        ls += p;
      }
    ls += __shfl_xor(ls, 32);
    l_run = l_run * sc_o + ls;

    // rescale O: lane's O rows are q = (r&3)+8*(r>>2)+4*hi -> broadcast via LDS
    red[w][l31] = sc_o;
#pragma unroll
    for (int r = 0; r < 16; ++r) {
      float f = red[w][(r & 3) + 8 * (r >> 2) + 4 * hi];
      accO[0][r] *= f;
      accO[1][r] *= f;
    }

    // P -> A-fragment (in-register, bf16 pack + 4 shfl per k-chunk) + PV
#pragma unroll
    for (int c = 0; c < 4; ++c) {
      int s = c >> 1, kk = c & 1;
      unsigned int x0 = pk2(sT[s][8 * kk + 0], sT[s][8 * kk + 1]);
      unsigned int y0 = pk2(sT[s][8 * kk + 2], sT[s][8 * kk + 3]);
      unsigned int x1 = pk2(sT[s][8 * kk + 4], sT[s][8 * kk + 5]);
      unsigned int y1 = pk2(sT[s][8 * kk + 6], sT[s][8 * kk + 7]);
      unsigned int sx0 = __shfl_xor(x0, 32), sy0 = __shfl_xor(y0, 32);
      unsigned int sx1 = __shfl_xor(x1, 32), sy1 = __shfl_xor(y1, 32);
      union { unsigned int u[4]; s16x8 v; } pf;
      pf.u[0] = hi ? sx1 : x0;
      pf.u[1] = hi ? sy1 : y0;
      pf.u[2] = hi ? x1 : sx0;
      pf.u[3] = hi ? y1 : sy0;
#pragma unroll
      for (int dt = 0; dt < 2; ++dt) {
        s16x8 vf = *(const s16x8*)(vbase + (dt * 32 + l31) * 128 +
                                   ((c * 32 + hi * 16) ^ (l7 << 4)));
        accO[dt] = __builtin_amdgcn_mfma_f32_32x32x16_bf16(pf.v, vf, accO[dt], 0, 0, 0);
      }
    }
  }

  // epilogue: O[q][d] with q = (r&3)+8*(r>>2)+4*hi, d = dt*32 + l31
  float inv = 1.0f / l_run;
  red[w][l31] = inv;
#pragma unroll
  for (int r = 0; r < 16; ++r) {
    int R = (r & 3) + 8 * (r >> 2) + 4 * hi;
    float f = red[w][R];
    int qg = qw + R;
    size_t base = ((size_t)b * TQ_ + qg) * DM_ + h * DH_ + l31;
    Ob[base] = f2bf(accO[0][r] * f);
    Ob[base + 32] = f2bf(accO[1][r] * f);
  }
}

extern "C" void kernel_launch(void* const* d_in, const int* in_sizes, int n_in,
                              void* d_out, int out_size, void* d_ws, size_t ws_size,
                              hipStream_t stream) {
  const float* xq  = (const float*)d_in[0];
  const float* xkv = (const float*)d_in[1];
  const unsigned char* mask = (const unsigned char*)d_in[2];
  const float* Wq  = (const float*)d_in[3];
  const float* bq  = (const float*)d_in[4];
  const float* Wkv = (const float*)d_in[5];
  const float* bkv = (const float*)d_in[6];
  const float* Wo  = (const float*)d_in[7];
  const float* bo  = (const float*)d_in[8];
  const int* cflag = (const int*)d_in[9];
  float* out = (float*)d_out;

  char* ws = (char*)d_ws;
  unsigned short* WqT  = (unsigned short*)(ws);                       // 2 MiB
  unsigned short* WkvT = (unsigned short*)(ws + ((size_t)2 << 20));   // 4 MiB
  unsigned short* WoT  = (unsigned short*)(ws + ((size_t)6 << 20));   // 2 MiB
  unsigned short* Qb   = (unsigned short*)(ws + ((size_t)8 << 20));   // [B,H,TQ,64]
  unsigned short* Kb   = (unsigned short*)(ws + ((size_t)24 << 20));  // [B,H,TKV,64]
  unsigned short* Vb   = (unsigned short*)(ws + ((size_t)40 << 20));  // [B,H,64,TKV]
  unsigned short* Ob   = (unsigned short*)(ws + ((size_t)56 << 20));  // [B,TQ,1024]

  k_transpose_cast<<<dim3(16, 16), 256, 0, stream>>>(Wq, WqT, 1024, 1024);
  k_transpose_cast<<<dim3(32, 16), 256, 0, stream>>>(Wkv, WkvT, 1024, 2048);
  k_transpose_cast<<<dim3(16, 16), 256, 0, stream>>>(Wo, WoT, 1024, 1024);

  k_gemm<0, false><<<dim3(8, 64), 256, 0, stream>>>(xq, WqT, bq, Qb, nullptr, nullptr, 1024);
  k_gemm<1, false><<<dim3(16, 64), 256, 0, stream>>>(xkv, WkvT, bkv, Kb, Vb, nullptr, 1024);

  k_attn<<<dim3(TQ_ / 128, B_ * H_), 256, 0, stream>>>(Qb, Kb, Vb, mask, cflag, Ob);

  k_gemm<2, true><<<dim3(8, 64), 256, 0, stream>>>(Ob, WoT, bo, nullptr, nullptr, out, 1024);
}

// Round 3
// 247.684 us; speedup vs baseline: 2.3634x; 1.3919x over previous
//
#include <hip/hip_runtime.h>
#include <hip/hip_bf16.h>

#define B_   4
#define TQ_  2048
#define TKV_ 2048
#define DM_  1024
#define H_   16
#define DH_  64

// 1/sqrt(DK) * log2(e), folded into Wq/bq so attention exp2 needs no scaling
#define SC_FOLD 0.18033688011112042f

using f32x4  = __attribute__((ext_vector_type(4))) float;
using f32x16 = __attribute__((ext_vector_type(16))) float;
using s16x8  = __attribute__((ext_vector_type(8))) short;

static __device__ __forceinline__ unsigned short f2bf(float f) {
  union { float f; unsigned int u; } v; v.f = f;
  unsigned int r = v.u + 0x7FFFu + ((v.u >> 16) & 1u);
  return (unsigned short)(r >> 16);
}
// packed f32 pair -> 2xbf16 (RNE) in one instruction
static __device__ __forceinline__ unsigned int pk2(float a, float b) {
  unsigned int r;
  asm("v_cvt_pk_bf16_f32 %0, %1, %2" : "=v"(r) : "v"(a), "v"(b));
  return r;
}

// ---------------- transpose + cast + scale: W[K][N] f32 -> WT[N][K] bf16 ----------------
__global__ __launch_bounds__(256) void k_transpose_cast(
    const float* __restrict__ W, unsigned short* __restrict__ WT, int K, int N,
    float scale) {
  __shared__ float t[64][65];
  int n0 = blockIdx.x * 64, k0 = blockIdx.y * 64;
  int tx = threadIdx.x & 63, ty = threadIdx.x >> 6;
#pragma unroll
  for (int i = 0; i < 64; i += 4)
    t[ty + i][tx] = W[(size_t)(k0 + ty + i) * N + n0 + tx];
  __syncthreads();
#pragma unroll
  for (int i = 0; i < 64; i += 4)
    WT[(size_t)(n0 + ty + i) * K + k0 + tx] = f2bf(t[tx][ty + i] * scale);
}

// ---------------- elementwise cast f32 -> bf16 ----------------
__global__ __launch_bounds__(256) void k_cast_bf16(
    const float* __restrict__ in, unsigned short* __restrict__ out, int n4) {
  for (int i = blockIdx.x * 256 + threadIdx.x; i < n4; i += gridDim.x * 256) {
    f32x4 v = *(const f32x4*)(in + (size_t)i * 4);
    unsigned long long u = (unsigned long long)pk2(v[0], v[1]) |
                           ((unsigned long long)pk2(v[2], v[3]) << 32);
    *(unsigned long long*)(out + (size_t)i * 4) = u;
  }
}

// ---------------- GEMM: C[m][n] = A[m][:] . BT[n][:] + bias[n]*bscale ----------------
// MODE 0: write Q [B,H,T,64] bf16
// MODE 1: write K [B,H,T,64] bf16, V TRANSPOSED [B,H,64,TKV] bf16
// MODE 2: write fp32 out [m][n]
template <int MODE, bool A_BF16>
__global__ __launch_bounds__(256) void k_gemm(
    const void* __restrict__ Ap, const unsigned short* __restrict__ BT,
    const float* __restrict__ bias, float bscale, unsigned short* __restrict__ out_a,
    unsigned short* __restrict__ out_b, float* __restrict__ out_f, int Kd) {
  __shared__ unsigned short As[128][40];
  __shared__ unsigned short Bs[128][40];
  int tid = threadIdx.x;
  int lane = tid & 63;
  int wv = tid >> 6;
  int wm = wv >> 1, wn = wv & 1;
  int m0 = blockIdx.y * 128, n0 = blockIdx.x * 128;

  f32x4 acc[4][4];
#pragma unroll
  for (int i = 0; i < 4; ++i)
#pragma unroll
    for (int j = 0; j < 4; ++j) acc[i][j] = (f32x4){0.f, 0.f, 0.f, 0.f};

  for (int k0 = 0; k0 < Kd; k0 += 32) {
    if (A_BF16) {
      const unsigned short* A = (const unsigned short*)Ap;
#pragma unroll
      for (int i = 0; i < 2; ++i) {
        int row = i * 64 + (tid >> 2);
        int c = (tid & 3) * 8;
        s16x8 v = *(const s16x8*)(A + (size_t)(m0 + row) * Kd + k0 + c);
        *(s16x8*)(&As[row][c]) = v;
      }
    } else {
      const float* A = (const float*)Ap;
#pragma unroll
      for (int i = 0; i < 4; ++i) {
        int row = i * 32 + (tid >> 3);
        int c = (tid & 7) * 4;
        f32x4 g = *(const f32x4*)(A + (size_t)(m0 + row) * Kd + k0 + c);
        unsigned long long u = (unsigned long long)pk2(g[0], g[1]) |
                               ((unsigned long long)pk2(g[2], g[3]) << 32);
        *(unsigned long long*)(&As[row][c]) = u;
      }
    }
#pragma unroll
    for (int i = 0; i < 2; ++i) {
      int row = i * 64 + (tid >> 2);
      int c = (tid & 3) * 8;
      s16x8 v = *(const s16x8*)(BT + (size_t)(n0 + row) * Kd + k0 + c);
      *(s16x8*)(&Bs[row][c]) = v;
    }
    __syncthreads();
    s16x8 af[4], bf[4];
#pragma unroll
    for (int i = 0; i < 4; ++i) {
      af[i] = *(const s16x8*)(&As[wm * 64 + i * 16 + (lane & 15)][(lane >> 4) * 8]);
      bf[i] = *(const s16x8*)(&Bs[wn * 64 + i * 16 + (lane & 15)][(lane >> 4) * 8]);
    }
#pragma unroll
    for (int mi = 0; mi < 4; ++mi)
#pragma unroll
      for (int ni = 0; ni < 4; ++ni)
        acc[mi][ni] = __builtin_amdgcn_mfma_f32_16x16x32_bf16(af[mi], bf[ni], acc[mi][ni], 0, 0, 0);
    __syncthreads();
  }

#pragma unroll
  for (int mi = 0; mi < 4; ++mi) {
#pragma unroll
    for (int ni = 0; ni < 4; ++ni) {
      int col = n0 + wn * 64 + ni * 16 + (lane & 15);
      int rbase = m0 + wm * 64 + mi * 16 + (lane >> 4) * 4;
      float bv = bias[col] * bscale;
      if (MODE == 1 && col >= H_ * DH_) {
        int c2 = col - H_ * DH_;
        int h = c2 >> 6, d = c2 & 63;
        int b = rbase >> 11, t = rbase & 2047;
        union { unsigned short h4[4]; unsigned long long u; } p;
#pragma unroll
        for (int r = 0; r < 4; ++r) p.h4[r] = f2bf(acc[mi][ni][r] + bv);
        *(unsigned long long*)(out_b + ((((size_t)b * H_ + h) * DH_ + d) * TKV_ + t)) = p.u;
      } else {
#pragma unroll
        for (int r = 0; r < 4; ++r) {
          float v = acc[mi][ni][r] + bv;
          int m = rbase + r;
          if (MODE == 0) {
            int b = m >> 11, t = m & 2047;
            int h = col >> 6, d = col & 63;
            out_a[(((size_t)b * H_ + h) * TQ_ + t) * DH_ + d] = f2bf(v);
          } else if (MODE == 1) {
            int b = m >> 11, t = m & 2047;
            int h = col >> 6, d = col & 63;
            out_a[(((size_t)b * H_ + h) * TKV_ + t) * DH_ + d] = f2bf(v);
          } else {
            out_f[(size_t)m * DM_ + col] = v;
          }
        }
      }
    }
  }
}

// ---------------- flash attention, swapped-QK^T, paired q-tiles ----------------
// grid: (TQ/256, B*H); each block handles q-tiles bx and (NT-1-bx) -> uniform work.
// 256 threads = 4 waves x 32 q-rows, KV tiles of 64.
__global__ __launch_bounds__(256, 3) void k_attn(
    const unsigned short* __restrict__ Qb, const unsigned short* __restrict__ Kb,
    const unsigned short* __restrict__ Vtb, const unsigned char* __restrict__ mask,
    const int* __restrict__ cflag, unsigned short* __restrict__ Ob) {
  __shared__ __align__(16) unsigned short Kt[64 * 64];  // [kv][d], XOR-swizzled
  __shared__ __align__(16) unsigned short Vt[64 * 64];  // [d][kv], XOR-swizzled
  __shared__ float bias_lds[64];
  __shared__ float red[4][32];
  __shared__ int s_any;

  int bh = blockIdx.y;
  int b = bh >> 4, h = bh & 15;
  int bx = blockIdx.x;
  int tid = threadIdx.x, lane = tid & 63, w = tid >> 6;
  int hi = lane >> 5, l31 = lane & 31, l7 = lane & 7;
  const unsigned short* Qp = Qb + (size_t)bh * TQ_ * DH_;
  const char* Kp = (const char*)(Kb + (size_t)bh * TKV_ * DH_);
  const char* Vp = (const char*)(Vtb + (size_t)bh * DH_ * TKV_);
  const unsigned char* mp = mask + (size_t)b * TKV_;
  int causal = cflag[0];
  char* kbase = (char*)Kt;
  char* vbase = (char*)Vt;

  // does any padding-mask bit exist for this batch row? (wave-uniform)
  if (tid == 0) s_any = 0;
  __syncthreads();
  {
    int any = 0;
    for (int i = tid; i < TKV_; i += 256) any |= mp[i];
    if (any) s_any = 1;
  }
  __syncthreads();
  const int has_mask = s_any;

#pragma unroll 1
  for (int pass = 0; pass < 2; ++pass) {
    int qb = (pass ? (TQ_ / 128 - 1 - bx) : bx) * 128;
    int qw = qb + w * 32;
    int qrow = qw + l31;

    // Q B-fragments (lane: col q = l31, k = d = kk*16 + hi*8 .. +8)
    s16x8 bQ[4];
#pragma unroll
    for (int kk = 0; kk < 4; ++kk)
      bQ[kk] = *(const s16x8*)(Qp + (size_t)qrow * DH_ + kk * 16 + hi * 8);

    f32x16 accO[2];
#pragma unroll
    for (int i = 0; i < 16; ++i) { accO[0][i] = 0.f; accO[1][i] = 0.f; }
    float m_run = -INFINITY, l_run = 0.f;

    int kv_end = causal ? (qb + 128) : TKV_;

    for (int kv0 = 0; kv0 < kv_end; kv0 += 64) {
      __syncthreads();
      {  // stage K tile [64][64] and V^T tile [64][64], swizzled writes
        int row = tid >> 2;
        int cb0 = (tid & 3) * 16;
#pragma unroll
        for (int p = 0; p < 2; ++p) {
          int cb = cb0 + p * 64;
          int sw = cb ^ ((row & 7) << 4);
          s16x8 kvv = *(const s16x8*)(Kp + ((size_t)(kv0 + row) * 128 + cb));
          *(s16x8*)(kbase + row * 128 + sw) = kvv;
          s16x8 vvv = *(const s16x8*)(Vp + (((size_t)row * TKV_ + kv0) * 2 + cb));
          *(s16x8*)(vbase + row * 128 + sw) = vvv;
        }
        if (has_mask && tid < 64) bias_lds[tid] = mp[kv0 + tid] ? -1e30f : 0.0f;
      }
      __syncthreads();
      if (causal && kv0 >= qw + 32) continue;  // wave fully above diagonal

      // S^T = K . Q^T  (64 kv x 32 q per wave, two 32x32 sub-tiles)
      f32x16 sT[2];
#pragma unroll
      for (int i = 0; i < 16; ++i) { sT[0][i] = 0.f; sT[1][i] = 0.f; }
#pragma unroll
      for (int s = 0; s < 2; ++s) {
#pragma unroll
        for (int kk = 0; kk < 4; ++kk) {
          s16x8 aK = *(const s16x8*)(kbase + (s * 32 + l31) * 128 +
                                     ((kk * 32 + hi * 16) ^ (l7 << 4)));
          sT[s] = __builtin_amdgcn_mfma_f32_32x32x16_bf16(aK, bQ[kk], sT[s], 0, 0, 0);
        }
      }

      // masks (only when needed) + in-lane max over 32 regs
      int diag = causal && (kv0 + 64 > qw);  // wave-uniform
      float mx = -INFINITY;
      if (diag || has_mask) {
#pragma unroll
        for (int s = 0; s < 2; ++s)
#pragma unroll
          for (int r = 0; r < 16; ++r) {
            int kvloc = s * 32 + (r & 3) + 8 * (r >> 2) + 4 * hi;
            float sv = sT[s][r];
            if (has_mask) sv += bias_lds[kvloc];
            if (diag && (kv0 + kvloc) > qrow) sv = -1e30f;
            sT[s][r] = sv;
            mx = fmaxf(mx, sv);
          }
      } else {
#pragma unroll
        for (int s = 0; s < 2; ++s)
#pragma unroll
          for (int r = 0; r < 16; ++r) mx = fmaxf(mx, sT[s][r]);
      }
      mx = fmaxf(mx, __shfl_xor(mx, 32));

      // T13 defer-rescale: only rescale when running max grew by > 8 (log2 units)
      if (!__all(mx - m_run <= 8.0f)) {
        float mnew = fmaxf(m_run, mx);
        float sc_o = exp2f(m_run - mnew);
        m_run = mnew;
        l_run *= sc_o;
        red[w][l31] = sc_o;
#pragma unroll
        for (int r = 0; r < 16; ++r) {
          float f = red[w][(r & 3) + 8 * (r >> 2) + 4 * hi];
          accO[0][r] *= f;
          accO[1][r] *= f;
        }
      }

      float ls = 0.f;
#pragma unroll
      for (int s = 0; s < 2; ++s)
#pragma unroll
        for (int r = 0; r < 16; ++r) {
          float p = exp2f(sT[s][r] - m_run);
          sT[s][r] = p;
          ls += p;
        }
      ls += __shfl_xor(ls, 32);
      l_run += ls;

      // P -> A-fragment (in-register cvt_pk + 4 shfl per k-chunk) + PV
#pragma unroll
      for (int c = 0; c < 4; ++c) {
        int s = c >> 1, kk = c & 1;
        unsigned int x0 = pk2(sT[s][8 * kk + 0], sT[s][8 * kk + 1]);
        unsigned int y0 = pk2(sT[s][8 * kk + 2], sT[s][8 * kk + 3]);
        unsigned int x1 = pk2(sT[s][8 * kk + 4], sT[s][8 * kk + 5]);
        unsigned int y1 = pk2(sT[s][8 * kk + 6], sT[s][8 * kk + 7]);
        unsigned int sx0 = __shfl_xor(x0, 32), sy0 = __shfl_xor(y0, 32);
        unsigned int sx1 = __shfl_xor(x1, 32), sy1 = __shfl_xor(y1, 32);
        union { unsigned int u[4]; s16x8 v; } pf;
        pf.u[0] = hi ? sx1 : x0;
        pf.u[1] = hi ? sy1 : y0;
        pf.u[2] = hi ? x1 : sx0;
        pf.u[3] = hi ? y1 : sy0;
#pragma unroll
        for (int dt = 0; dt < 2; ++dt) {
          s16x8 vf = *(const s16x8*)(vbase + (dt * 32 + l31) * 128 +
                                     ((c * 32 + hi * 16) ^ (l7 << 4)));
          accO[dt] = __builtin_amdgcn_mfma_f32_32x32x16_bf16(pf.v, vf, accO[dt], 0, 0, 0);
        }
      }
    }

    // epilogue: O[q][d] with q = (r&3)+8*(r>>2)+4*hi, d = dt*32 + l31
    red[w][l31] = 1.0f / l_run;
#pragma unroll
    for (int r = 0; r < 16; ++r) {
      int R = (r & 3) + 8 * (r >> 2) + 4 * hi;
      float f = red[w][R];
      int qg = qw + R;
      size_t base = ((size_t)b * TQ_ + qg) * DM_ + h * DH_ + l31;
      Ob[base] = f2bf(accO[0][r] * f);
      Ob[base + 32] = f2bf(accO[1][r] * f);
    }
  }
}

extern "C" void kernel_launch(void* const* d_in, const int* in_sizes, int n_in,
                              void* d_out, int out_size, void* d_ws, size_t ws_size,
                              hipStream_t stream) {
  const float* xq  = (const float*)d_in[0];
  const float* xkv = (const float*)d_in[1];
  const unsigned char* mask = (const unsigned char*)d_in[2];
  const float* Wq  = (const float*)d_in[3];
  const float* bq  = (const float*)d_in[4];
  const float* Wkv = (const float*)d_in[5];
  const float* bkv = (const float*)d_in[6];
  const float* Wo  = (const float*)d_in[7];
  const float* bo  = (const float*)d_in[8];
  const int* cflag = (const int*)d_in[9];
  float* out = (float*)d_out;

  char* ws = (char*)d_ws;
  unsigned short* WqT  = (unsigned short*)(ws);                       // 2 MiB
  unsigned short* WkvT = (unsigned short*)(ws + ((size_t)2 << 20));   // 4 MiB
  unsigned short* WoT  = (unsigned short*)(ws + ((size_t)6 << 20));   // 2 MiB
  unsigned short* Qb   = (unsigned short*)(ws + ((size_t)8 << 20));   // [B,H,TQ,64]
  unsigned short* Kb   = (unsigned short*)(ws + ((size_t)24 << 20));  // [B,H,TKV,64]
  unsigned short* Vb   = (unsigned short*)(ws + ((size_t)40 << 20));  // [B,H,64,TKV]
  // Aq (bf16 xq) and Ob share the last 16 MiB: Aq dead after Q-proj, Ob born at attn
  unsigned short* Aq   = (unsigned short*)(ws + ((size_t)56 << 20));
  unsigned short* Ob   = Aq;

  k_transpose_cast<<<dim3(16, 16), 256, 0, stream>>>(Wq, WqT, 1024, 1024, SC_FOLD);
  k_transpose_cast<<<dim3(32, 16), 256, 0, stream>>>(Wkv, WkvT, 1024, 2048, 1.0f);
  k_transpose_cast<<<dim3(16, 16), 256, 0, stream>>>(Wo, WoT, 1024, 1024, 1.0f);

  k_cast_bf16<<<2048, 256, 0, stream>>>(xq, Aq, B_ * TQ_ * DM_ / 4);

  k_gemm<0, true><<<dim3(8, 64), 256, 0, stream>>>(Aq, WqT, bq, SC_FOLD, Qb, nullptr, nullptr, 1024);
  k_gemm<1, false><<<dim3(16, 64), 256, 0, stream>>>(xkv, WkvT, bkv, 1.0f, Kb, Vb, nullptr, 1024);

  k_attn<<<dim3(TQ_ / 256, B_ * H_), 256, 0, stream>>>(Qb, Kb, Vb, mask, cflag, Ob);

  k_gemm<2, true><<<dim3(8, 64), 256, 0, stream>>>(Ob, WoT, bo, 1.0f, nullptr, nullptr, out, 1024);
}

// Round 4
// 231.127 us; speedup vs baseline: 2.5327x; 1.0716x over previous
//
#include <hip/hip_runtime.h>
#include <hip/hip_bf16.h>

#define B_   4
#define TQ_  2048
#define TKV_ 2048
#define DM_  1024
#define H_   16
#define DH_  64

// 1/sqrt(DK) * log2(e), folded into Wq/bq so attention exp2 needs no scaling
#define SC_FOLD 0.18033688011112042f

using f32x4  = __attribute__((ext_vector_type(4))) float;
using f32x16 = __attribute__((ext_vector_type(16))) float;
using s16x8  = __attribute__((ext_vector_type(8))) short;

static __device__ __forceinline__ unsigned short f2bf(float f) {
  union { float f; unsigned int u; } v; v.f = f;
  unsigned int r = v.u + 0x7FFFu + ((v.u >> 16) & 1u);
  return (unsigned short)(r >> 16);
}
// packed f32 pair -> 2xbf16 (RNE) in one instruction
static __device__ __forceinline__ unsigned int pk2(float a, float b) {
  unsigned int r;
  asm("v_cvt_pk_bf16_f32 %0, %1, %2" : "=v"(r) : "v"(a), "v"(b));
  return r;
}

// async global->LDS, 16B per lane; LDS dest is wave-uniform base + lane*16
#define GL16(g, l)                                                          \
  __builtin_amdgcn_global_load_lds(                                         \
      (const __attribute__((address_space(1))) unsigned int*)(g),           \
      (__attribute__((address_space(3))) unsigned int*)(l), 16, 0, 0)

// ---------------- transpose + cast + scale: W[K][N] f32 -> WT[N][K] bf16 ----------------
__global__ __launch_bounds__(256) void k_transpose_cast(
    const float* __restrict__ W, unsigned short* __restrict__ WT, int K, int N,
    float scale) {
  __shared__ float t[64][65];
  int n0 = blockIdx.x * 64, k0 = blockIdx.y * 64;
  int tx = threadIdx.x & 63, ty = threadIdx.x >> 6;
#pragma unroll
  for (int i = 0; i < 64; i += 4)
    t[ty + i][tx] = W[(size_t)(k0 + ty + i) * N + n0 + tx];
  __syncthreads();
#pragma unroll
  for (int i = 0; i < 64; i += 4)
    WT[(size_t)(n0 + ty + i) * K + k0 + tx] = f2bf(t[tx][ty + i] * scale);
}

// ---------------- elementwise cast f32 -> bf16 ----------------
__global__ __launch_bounds__(256) void k_cast_bf16(
    const float* __restrict__ in, unsigned short* __restrict__ out, int n4) {
  for (int i = blockIdx.x * 256 + threadIdx.x; i < n4; i += gridDim.x * 256) {
    f32x4 v = *(const f32x4*)(in + (size_t)i * 4);
    unsigned long long u = (unsigned long long)pk2(v[0], v[1]) |
                           ((unsigned long long)pk2(v[2], v[3]) << 32);
    *(unsigned long long*)(out + (size_t)i * 4) = u;
  }
}

// ---------------- GEMM (m97 structure): C = A . BT^T + bias ----------------
// A bf16 [M][Kd], BT bf16 [N][Kd]. 128x128 tile, BK=32, global_load_lds staging.
// MODE 0: write Q [B,H,T,64] bf16
// MODE 1: write K [B,H,T,64] bf16, V TRANSPOSED [B,H,64,TKV] bf16
// MODE 2: write fp32 out [m][n]
template <int MODE>
__global__ __launch_bounds__(256) void k_gemm(
    const unsigned short* __restrict__ A, const unsigned short* __restrict__ BT,
    const float* __restrict__ bias, float bscale, unsigned short* __restrict__ out_a,
    unsigned short* __restrict__ out_b, float* __restrict__ out_f, int Kd) {
  __shared__ __align__(16) unsigned short As[128 * 32];
  __shared__ __align__(16) unsigned short Bs[128 * 32];
  int tid = threadIdx.x, lane = tid & 63, w = tid >> 6;
  int wm = w >> 1, wn = w & 1;

  // XCD-bijective blockIdx swizzle (nwg % 8 == 0 for all our grids)
  int nwg = gridDim.x * gridDim.y;
  int bid = blockIdx.y * gridDim.x + blockIdx.x;
  int cpx = nwg >> 3;
  int sw = (bid & 7) * cpx + (bid >> 3);
  int bx = sw % gridDim.x, by = sw / gridDim.x;
  int m0 = by * 128, n0 = bx * 128;

  // staging addresses: chunk c = w*2+i covers LDS rows [c*16, c*16+16)
  int srow = w * 32 + (lane >> 2);        // + i*16
  int scol = (lane & 3) * 8;
  const unsigned short* gA0 = A + (size_t)(m0 + srow) * Kd + scol;
  const unsigned short* gA1 = gA0 + (size_t)16 * Kd;
  const unsigned short* gB0 = BT + (size_t)(n0 + srow) * Kd + scol;
  const unsigned short* gB1 = gB0 + (size_t)16 * Kd;
  unsigned short* lA0 = As + w * 1024;
  unsigned short* lA1 = As + w * 1024 + 512;
  unsigned short* lB0 = Bs + w * 1024;
  unsigned short* lB1 = Bs + w * 1024 + 512;

  f32x4 acc[4][4];
#pragma unroll
  for (int i = 0; i < 4; ++i)
#pragma unroll
    for (int j = 0; j < 4; ++j) acc[i][j] = (f32x4){0.f, 0.f, 0.f, 0.f};

  for (int k0 = 0; k0 < Kd; k0 += 32) {
    __syncthreads();  // prior iteration's reads done
    GL16(gA0 + k0, lA0);
    GL16(gA1 + k0, lA1);
    GL16(gB0 + k0, lB0);
    GL16(gB1 + k0, lB1);
    __syncthreads();  // vmcnt drained -> tiles ready

    s16x8 af[4], bf[4];
#pragma unroll
    for (int i = 0; i < 4; ++i) {
      af[i] = *(const s16x8*)(As + (wm * 64 + i * 16 + (lane & 15)) * 32 + (lane >> 4) * 8);
      bf[i] = *(const s16x8*)(Bs + (wn * 64 + i * 16 + (lane & 15)) * 32 + (lane >> 4) * 8);
    }
#pragma unroll
    for (int mi = 0; mi < 4; ++mi)
#pragma unroll
      for (int ni = 0; ni < 4; ++ni)
        acc[mi][ni] = __builtin_amdgcn_mfma_f32_16x16x32_bf16(af[mi], bf[ni], acc[mi][ni], 0, 0, 0);
  }

#pragma unroll
  for (int mi = 0; mi < 4; ++mi) {
#pragma unroll
    for (int ni = 0; ni < 4; ++ni) {
      int col = n0 + wn * 64 + ni * 16 + (lane & 15);
      int rbase = m0 + wm * 64 + mi * 16 + (lane >> 4) * 4;
      float bv = bias[col] * bscale;
      if (MODE == 1 && col >= H_ * DH_) {
        int c2 = col - H_ * DH_;
        int h = c2 >> 6, d = c2 & 63;
        int b = rbase >> 11, t = rbase & 2047;
        union { unsigned short h4[4]; unsigned long long u; } p;
#pragma unroll
        for (int r = 0; r < 4; ++r) p.h4[r] = f2bf(acc[mi][ni][r] + bv);
        *(unsigned long long*)(out_b + ((((size_t)b * H_ + h) * DH_ + d) * TKV_ + t)) = p.u;
      } else {
#pragma unroll
        for (int r = 0; r < 4; ++r) {
          float v = acc[mi][ni][r] + bv;
          int m = rbase + r;
          if (MODE == 0) {
            int b = m >> 11, t = m & 2047;
            int h = col >> 6, d = col & 63;
            out_a[(((size_t)b * H_ + h) * TQ_ + t) * DH_ + d] = f2bf(v);
          } else if (MODE == 1) {
            int b = m >> 11, t = m & 2047;
            int h = col >> 6, d = col & 63;
            out_a[(((size_t)b * H_ + h) * TKV_ + t) * DH_ + d] = f2bf(v);
          } else {
            out_f[(size_t)m * DM_ + col] = v;
          }
        }
      }
    }
  }
}

// ---------------- flash attention, swapped-QK^T, paired q-tiles ----------------
// grid: (TQ/256, B*H); each block handles q-tiles bx and (NT-1-bx) -> uniform work.
// 256 threads = 4 waves x 32 q-rows, KV tiles of 64.
__global__ __launch_bounds__(256, 3) void k_attn(
    const unsigned short* __restrict__ Qb, const unsigned short* __restrict__ Kb,
    const unsigned short* __restrict__ Vtb, const unsigned char* __restrict__ mask,
    const int* __restrict__ cflag, unsigned short* __restrict__ Ob) {
  __shared__ __align__(16) unsigned short Kt[64 * 64];  // [kv][d], XOR-swizzled
  __shared__ __align__(16) unsigned short Vt[64 * 64];  // [d][kv], XOR-swizzled
  __shared__ float bias_lds[64];
  __shared__ float red[4][32];
  __shared__ int s_any;

  int bh = blockIdx.y;
  int b = bh >> 4, h = bh & 15;
  int bx = blockIdx.x;
  int tid = threadIdx.x, lane = tid & 63, w = tid >> 6;
  int hi = lane >> 5, l31 = lane & 31, l7 = lane & 7;
  const unsigned short* Qp = Qb + (size_t)bh * TQ_ * DH_;
  const char* Kp = (const char*)(Kb + (size_t)bh * TKV_ * DH_);
  const char* Vp = (const char*)(Vtb + (size_t)bh * DH_ * TKV_);
  const unsigned char* mp = mask + (size_t)b * TKV_;
  int causal = cflag[0];
  char* kbase = (char*)Kt;
  char* vbase = (char*)Vt;

  if (tid == 0) s_any = 0;
  __syncthreads();
  {
    int any = 0;
    for (int i = tid; i < TKV_; i += 256) any |= mp[i];
    if (any) s_any = 1;
  }
  __syncthreads();
  const int has_mask = s_any;

#pragma unroll 1
  for (int pass = 0; pass < 2; ++pass) {
    int qb = (pass ? (TQ_ / 128 - 1 - bx) : bx) * 128;
    int qw = qb + w * 32;
    int qrow = qw + l31;

    s16x8 bQ[4];
#pragma unroll
    for (int kk = 0; kk < 4; ++kk)
      bQ[kk] = *(const s16x8*)(Qp + (size_t)qrow * DH_ + kk * 16 + hi * 8);

    f32x16 accO[2];
#pragma unroll
    for (int i = 0; i < 16; ++i) { accO[0][i] = 0.f; accO[1][i] = 0.f; }
    float m_run = -INFINITY, l_run = 0.f;

    int kv_end = causal ? (qb + 128) : TKV_;

    for (int kv0 = 0; kv0 < kv_end; kv0 += 64) {
      __syncthreads();
      {
        int row = tid >> 2;
        int cb0 = (tid & 3) * 16;
#pragma unroll
        for (int p = 0; p < 2; ++p) {
          int cb = cb0 + p * 64;
          int sw = cb ^ ((row & 7) << 4);
          s16x8 kvv = *(const s16x8*)(Kp + ((size_t)(kv0 + row) * 128 + cb));
          *(s16x8*)(kbase + row * 128 + sw) = kvv;
          s16x8 vvv = *(const s16x8*)(Vp + (((size_t)row * TKV_ + kv0) * 2 + cb));
          *(s16x8*)(vbase + row * 128 + sw) = vvv;
        }
        if (has_mask && tid < 64) bias_lds[tid] = mp[kv0 + tid] ? -1e30f : 0.0f;
      }
      __syncthreads();
      if (causal && kv0 >= qw + 32) continue;

      f32x16 sT[2];
#pragma unroll
      for (int i = 0; i < 16; ++i) { sT[0][i] = 0.f; sT[1][i] = 0.f; }
#pragma unroll
      for (int s = 0; s < 2; ++s) {
#pragma unroll
        for (int kk = 0; kk < 4; ++kk) {
          s16x8 aK = *(const s16x8*)(kbase + (s * 32 + l31) * 128 +
                                     ((kk * 32 + hi * 16) ^ (l7 << 4)));
          sT[s] = __builtin_amdgcn_mfma_f32_32x32x16_bf16(aK, bQ[kk], sT[s], 0, 0, 0);
        }
      }

      int diag = causal && (kv0 + 64 > qw);
      float mx = -INFINITY;
      if (diag || has_mask) {
#pragma unroll
        for (int s = 0; s < 2; ++s)
#pragma unroll
          for (int r = 0; r < 16; ++r) {
            int kvloc = s * 32 + (r & 3) + 8 * (r >> 2) + 4 * hi;
            float sv = sT[s][r];
            if (has_mask) sv += bias_lds[kvloc];
            if (diag && (kv0 + kvloc) > qrow) sv = -1e30f;
            sT[s][r] = sv;
            mx = fmaxf(mx, sv);
          }
      } else {
#pragma unroll
        for (int s = 0; s < 2; ++s)
#pragma unroll
          for (int r = 0; r < 16; ++r) mx = fmaxf(mx, sT[s][r]);
      }
      mx = fmaxf(mx, __shfl_xor(mx, 32));

      if (!__all(mx - m_run <= 8.0f)) {
        float mnew = fmaxf(m_run, mx);
        float sc_o = exp2f(m_run - mnew);
        m_run = mnew;
        l_run *= sc_o;
        red[w][l31] = sc_o;
#pragma unroll
        for (int r = 0; r < 16; ++r) {
          float f = red[w][(r & 3) + 8 * (r >> 2) + 4 * hi];
          accO[0][r] *= f;
          accO[1][r] *= f;
        }
      }

      float ls = 0.f;
#pragma unroll
      for (int s = 0; s < 2; ++s)
#pragma unroll
        for (int r = 0; r < 16; ++r) {
          float p = exp2f(sT[s][r] - m_run);
          sT[s][r] = p;
          ls += p;
        }
      ls += __shfl_xor(ls, 32);
      l_run += ls;

#pragma unroll
      for (int c = 0; c < 4; ++c) {
        int s = c >> 1, kk = c & 1;
        unsigned int x0 = pk2(sT[s][8 * kk + 0], sT[s][8 * kk + 1]);
        unsigned int y0 = pk2(sT[s][8 * kk + 2], sT[s][8 * kk + 3]);
        unsigned int x1 = pk2(sT[s][8 * kk + 4], sT[s][8 * kk + 5]);
        unsigned int y1 = pk2(sT[s][8 * kk + 6], sT[s][8 * kk + 7]);
        unsigned int sx0 = __shfl_xor(x0, 32), sy0 = __shfl_xor(y0, 32);
        unsigned int sx1 = __shfl_xor(x1, 32), sy1 = __shfl_xor(y1, 32);
        union { unsigned int u[4]; s16x8 v; } pf;
        pf.u[0] = hi ? sx1 : x0;
        pf.u[1] = hi ? sy1 : y0;
        pf.u[2] = hi ? x1 : sx0;
        pf.u[3] = hi ? y1 : sy0;
#pragma unroll
        for (int dt = 0; dt < 2; ++dt) {
          s16x8 vf = *(const s16x8*)(vbase + (dt * 32 + l31) * 128 +
                                     ((c * 32 + hi * 16) ^ (l7 << 4)));
          accO[dt] = __builtin_amdgcn_mfma_f32_32x32x16_bf16(pf.v, vf, accO[dt], 0, 0, 0);
        }
      }
    }

    red[w][l31] = 1.0f / l_run;
#pragma unroll
    for (int r = 0; r < 16; ++r) {
      int R = (r & 3) + 8 * (r >> 2) + 4 * hi;
      float f = red[w][R];
      int qg = qw + R;
      size_t base = ((size_t)b * TQ_ + qg) * DM_ + h * DH_ + l31;
      Ob[base] = f2bf(accO[0][r] * f);
      Ob[base + 32] = f2bf(accO[1][r] * f);
    }
  }
}

extern "C" void kernel_launch(void* const* d_in, const int* in_sizes, int n_in,
                              void* d_out, int out_size, void* d_ws, size_t ws_size,
                              hipStream_t stream) {
  const float* xq  = (const float*)d_in[0];
  const float* xkv = (const float*)d_in[1];
  const unsigned char* mask = (const unsigned char*)d_in[2];
  const float* Wq  = (const float*)d_in[3];
  const float* bq  = (const float*)d_in[4];
  const float* Wkv = (const float*)d_in[5];
  const float* bkv = (const float*)d_in[6];
  const float* Wo  = (const float*)d_in[7];
  const float* bo  = (const float*)d_in[8];
  const int* cflag = (const int*)d_in[9];
  float* out = (float*)d_out;

  char* ws = (char*)d_ws;
  unsigned short* WqT  = (unsigned short*)(ws);                       // 2 MiB
  unsigned short* WkvT = (unsigned short*)(ws + ((size_t)2 << 20));   // 4 MiB
  unsigned short* WoT  = (unsigned short*)(ws + ((size_t)6 << 20));   // 2 MiB
  unsigned short* Qb   = (unsigned short*)(ws + ((size_t)8 << 20));   // [B,H,TQ,64]
  unsigned short* Kb   = (unsigned short*)(ws + ((size_t)24 << 20));  // [B,H,TKV,64]
  unsigned short* Vb   = (unsigned short*)(ws + ((size_t)40 << 20));  // [B,H,64,TKV]
  // region X (16 MiB): Aq (xq bf16) -> Akv (xkv bf16) -> Ob ; live ranges disjoint
  unsigned short* Xr   = (unsigned short*)(ws + ((size_t)56 << 20));
  unsigned short* Ob   = Xr;

  k_transpose_cast<<<dim3(16, 16), 256, 0, stream>>>(Wq, WqT, 1024, 1024, SC_FOLD);
  k_transpose_cast<<<dim3(32, 16), 256, 0, stream>>>(Wkv, WkvT, 1024, 2048, 1.0f);
  k_transpose_cast<<<dim3(16, 16), 256, 0, stream>>>(Wo, WoT, 1024, 1024, 1.0f);

  // Q-proj (A = bf16 xq staged in region X)
  k_cast_bf16<<<2048, 256, 0, stream>>>(xq, Xr, B_ * TQ_ * DM_ / 4);
  k_gemm<0><<<dim3(8, 64), 256, 0, stream>>>(Xr, WqT, bq, SC_FOLD, Qb, nullptr, nullptr, 1024);

  // KV-proj (A = bf16 xkv, reusing region X after Q-proj consumed it)
  k_cast_bf16<<<2048, 256, 0, stream>>>(xkv, Xr, B_ * TKV_ * DM_ / 4);
  k_gemm<1><<<dim3(16, 64), 256, 0, stream>>>(Xr, WkvT, bkv, 1.0f, Kb, Vb, nullptr, 1024);

  // attention (writes Ob into region X; bf16 xkv dead by now)
  k_attn<<<dim3(TQ_ / 256, B_ * H_), 256, 0, stream>>>(Qb, Kb, Vb, mask, cflag, Ob);

  // output projection
  k_gemm<2><<<dim3(8, 64), 256, 0, stream>>>(Ob, WoT, bo, 1.0f, nullptr, nullptr, out, 1024);
}